// Round 13
// baseline (174.186 us; speedup 1.0000x reference)
//
#include <hip/hip_runtime.h>
#include <hip/hip_bf16.h>

// ShuffleNet fused block-MLP, MI355X (gfx950).  R13: ABLATION ROUND.
// Four template variants dispatched back-to-back (per-dispatch rocprof rows
// give each variant's isolated duration); real kernel (V0) runs LAST -> y.
//  V0: full fused (R11 math + XCD-aligned decode + nontemporal x)  -> y
//  V1: V0 minus GELU (bias+pack kept)                              -> yc (ws)
//  V2: GEMM1+gelu+pack+store only (no bf loads, no GEMM2)          -> g16 (ws)
//  V3: GEMM2 only (A-frag = ds_read of staged x; no w1/b1/gelu)    -> yc (ws)
// All variants: grid 2048, block 256, launch_bounds(256,4), same decode
// rt = b&511 (x-sharing WGs 512 apart -> same XCD), np = (b>>9)*4 + wv.

typedef __attribute__((ext_vector_type(8))) short  short8;   // 8 bf16 = 4 VGPR
typedef __attribute__((ext_vector_type(4))) short  short4v;
typedef __attribute__((ext_vector_type(4))) float  floatx4;

#define XP 1032   // xs row pitch in shorts (516 dw = 4 mod 32 -> bank rotation)

__device__ __forceinline__ short f2bf(float f) {
  union { __hip_bfloat16 h; short s; } u;
  u.h = __float2bfloat16(f);
  return u.s;
}
__device__ __forceinline__ float bf2f(short s) {
  union { float f; unsigned u; } uu;
  uu.u = ((unsigned)(unsigned short)s) << 16;
  return uu.f;
}
__device__ __forceinline__ int pk16(float a, float b) {
  return (int)(unsigned short)f2bf(a) | ((int)(unsigned short)f2bf(b) << 16);
}

// gelu(v) ~= v * sigmoid(1.5957691*(v + 0.044715 v^3)), exp2-folded (abs<5e-4)
__device__ __forceinline__ float gelu_f(float v) {
  float m = v * v;
  float c = fmaf(-0.1029375f, m, -2.3020807f);
  float z = v * c;
  float e = __builtin_amdgcn_exp2f(z);
  return v * __builtin_amdgcn_rcpf(1.0f + e);
}

// ---- pack kernel: w1 frags | w2 frags (pi-permuted) | b1 frags (bf16) ----
__global__ void pack_k(const float* __restrict__ w1, const float* __restrict__ w2,
                       const float* __restrict__ b1, short* __restrict__ w1p,
                       short* __restrict__ w2p, short* __restrict__ b1p) {
  const int t = blockIdx.x * blockDim.x + threadIdx.x;  // 160*512 = 81920
  const int lane = t & 63;
  const int lhi = lane >> 4;
  if (t < 32768) {  // w1 frag (n,np,ks)
    const int ks = (t >> 6) & 1, np = (t >> 7) & 15, n = (t >> 11) & 15;
    const float* src = w1 + ((size_t)(n * 256 + np * 16 + (lane & 15)) * 64 + ks * 32 + lhi * 8);
    short8 f;
#pragma unroll
    for (int e = 0; e < 8; ++e) f[e] = f2bf(src[e]);
    *(short8*)(w1p + (size_t)t * 8) = f;
  } else if (t < 65536) {  // w2 frag (np,s,ot), pi-permuted k
    const int t2 = t - 32768;
    const int ot = (t2 >> 6) & 3, s = (t2 >> 8) & 7, np = (t2 >> 11) & 15;
    const int op = ot * 16 + (lane & 15);
    short8 f;
#pragma unroll
    for (int e = 0; e < 8; ++e) {
      const int Kc = 32 * s + 16 * ((e >> 2) & 1) + 4 * lhi + (e & 3);
      const int n = Kc >> 4, ohi = Kc & 15;
      f[e] = f2bf(w2[(size_t)(np * 64 + op) * 256 + ohi * 16 + n]);
    }
    *(short8*)(w2p + (size_t)t2 * 8) = f;
  } else {  // b1 frag (n,np)
    const int t3 = t - 65536;  // 16384
    const int np = (t3 >> 6) & 15, n = (t3 >> 10) & 15;
    short4v b;
#pragma unroll
    for (int r = 0; r < 4; ++r) b[r] = f2bf(b1[(np * 16 + lhi * 4 + r) * 16 + n]);
    *(short4v*)(b1p + (size_t)((n * 16 + np) * 64 + lane) * 4) = b;
  }
}

// ---- fused variants ----
template <int V>
__global__ __launch_bounds__(256, 4) void fused_t(
    const float* __restrict__ x, const short* __restrict__ w1p,
    const short* __restrict__ w2p, const short* __restrict__ b1p,
    const float* __restrict__ b2, float* __restrict__ y,
    short* __restrict__ g16, float* __restrict__ yc) {
  __shared__ __align__(16) short xs[16 * XP];   // 33 KB staged x

  const int tid = threadIdx.x;
  const int wv = tid >> 6, lane = tid & 63;
  const int l15 = lane & 15, lhi = lane >> 4;
  const int rt  = blockIdx.x & 511;
  const int np  = (blockIdx.x >> 9) * 4 + wv;

  // stage: 16 rows x 1024 f32 -> bf16 LDS (nontemporal, coalesced)
#pragma unroll
  for (int p = 0; p < 4; ++p) {
    const int row = wv * 4 + p;
#pragma unroll
    for (int q = 0; q < 4; ++q) {
      const int col = q * 256 + lane * 4;
      floatx4 v = __builtin_nontemporal_load(
          (const floatx4*)(x + (size_t)(rt * 16 + row) * 1024 + col));
      short4v sv;
#pragma unroll
      for (int e = 0; e < 4; ++e) sv[e] = f2bf(v[e]);
      *(short4v*)(&xs[row * XP + col]) = sv;
    }
  }
  __syncthreads();

  floatx4 c0 = {0.f,0.f,0.f,0.f}, c1 = {0.f,0.f,0.f,0.f};
  floatx4 c2 = {0.f,0.f,0.f,0.f}, c3 = {0.f,0.f,0.f,0.f};

#pragma unroll
  for (int s = 0; s < 8; ++s) {
    union { int i[4]; short8 v; } af;

    if constexpr (V != 3) {
      // GEMM1 block n=2s and n=2s+1
#pragma unroll
      for (int half = 0; half < 2; ++half) {
        const int n = 2 * s + half;
        short8 xf0 = *(const short8*)(&xs[l15 * XP + n * 64 + lhi * 8]);
        short8 xf1 = *(const short8*)(&xs[l15 * XP + n * 64 + 32 + lhi * 8]);
        short8 wf0 = *(const short8*)(w1p + (size_t)(((n * 16 + np) * 2 + 0) * 64 + lane) * 8);
        short8 wf1 = *(const short8*)(w1p + (size_t)(((n * 16 + np) * 2 + 1) * 64 + lane) * 8);
        short4v bv = *(const short4v*)(b1p + (size_t)((n * 16 + np) * 64 + lane) * 4);
        floatx4 acc = {0.f, 0.f, 0.f, 0.f};
        acc = __builtin_amdgcn_mfma_f32_16x16x32_bf16(wf0, xf0, acc, 0, 0, 0);
        acc = __builtin_amdgcn_mfma_f32_16x16x32_bf16(wf1, xf1, acc, 0, 0, 0);
        float g0, g1, g2, g3;
        if constexpr (V == 1) {   // no-gelu variant: bias only
          g0 = acc[0] + bf2f(bv[0]); g1 = acc[1] + bf2f(bv[1]);
          g2 = acc[2] + bf2f(bv[2]); g3 = acc[3] + bf2f(bv[3]);
        } else {
          g0 = gelu_f(acc[0] + bf2f(bv[0])); g1 = gelu_f(acc[1] + bf2f(bv[1]));
          g2 = gelu_f(acc[2] + bf2f(bv[2])); g3 = gelu_f(acc[3] + bf2f(bv[3]));
        }
        af.i[2 * half + 0] = pk16(g0, g1);
        af.i[2 * half + 1] = pk16(g2, g3);
      }
    } else {
      // V3: A-frag straight from staged x (data-dependent; no w1/gelu)
      af.v = *(const short8*)(&xs[l15 * XP + 2 * s * 64 + lhi * 8]);
    }

    if constexpr (V == 2) {
      // store packed gelu output (contiguous 1KB/wave-inst); no GEMM2
      *(short8*)(g16 + ((((size_t)blockIdx.x * 4 + wv) * 8 + s) * 64 + lane) * 8) = af.v;
    } else {
      const size_t wb = (size_t)((np * 8 + s) * 4) * 64 * 8;
      short8 bf0 = *(const short8*)(w2p + wb + (size_t)(0 * 64 + lane) * 8);
      short8 bf1 = *(const short8*)(w2p + wb + (size_t)(1 * 64 + lane) * 8);
      short8 bf2v = *(const short8*)(w2p + wb + (size_t)(2 * 64 + lane) * 8);
      short8 bf3 = *(const short8*)(w2p + wb + (size_t)(3 * 64 + lane) * 8);
      c0 = __builtin_amdgcn_mfma_f32_16x16x32_bf16(af.v, bf0, c0, 0, 0, 0);
      c1 = __builtin_amdgcn_mfma_f32_16x16x32_bf16(af.v, bf1, c1, 0, 0, 0);
      c2 = __builtin_amdgcn_mfma_f32_16x16x32_bf16(af.v, bf2v, c2, 0, 0, 0);
      c3 = __builtin_amdgcn_mfma_f32_16x16x32_bf16(af.v, bf3, c3, 0, 0, 0);
    }
  }

  if constexpr (V != 2) {
    float* out = (V == 0) ? y : yc;
    floatx4 cc[4] = {c0, c1, c2, c3};
#pragma unroll
    for (int ot = 0; ot < 4; ++ot) {
      const int col = np * 64 + ot * 16 + l15;
      const float bb = b2[col];
      float* py = out + (size_t)(rt * 16 + lhi * 4) * 1024 + col;
#pragma unroll
      for (int r = 0; r < 4; ++r)
        py[(size_t)r * 1024] = cc[ot][r] + bb;
    }
  }
}

extern "C" void kernel_launch(void* const* d_in, const int* in_sizes, int n_in,
                              void* d_out, int out_size, void* d_ws, size_t ws_size,
                              hipStream_t stream) {
  const float* x  = (const float*)d_in[0];
  const float* w1 = (const float*)d_in[1];
  const float* b1 = (const float*)d_in[2];
  const float* w2 = (const float*)d_in[3];
  const float* b2 = (const float*)d_in[4];
  float* y = (float*)d_out;

  short* w1p = (short*)d_ws;               // 512 KB
  short* w2p = w1p + 16 * 256 * 64;        // 512 KB
  short* b1p = w2p + 16 * 256 * 64;        // 128 KB
  short* g16 = b1p + 16 * 16 * 64 * 4;     // 64 MB scratch (shared by variants)
  float* yc  = (float*)g16;                // alias: different dispatches

  pack_k<<<160, 512, 0, stream>>>(w1, w2, b1, w1p, w2p, b1p);
  // ablation dispatches (outputs -> ws scratch, never validated)
  fused_t<1><<<2048, 256, 0, stream>>>(x, w1p, w2p, b1p, b2, y, g16, yc);
  fused_t<2><<<2048, 256, 0, stream>>>(x, w1p, w2p, b1p, b2, y, g16, yc);
  fused_t<3><<<2048, 256, 0, stream>>>(x, w1p, w2p, b1p, b2, y, g16, yc);
  // real kernel LAST -> d_out correct
  fused_t<0><<<2048, 256, 0, stream>>>(x, w1p, w2p, b1p, b2, y, g16, yc);
}

// Round 14
// 113.801 us; speedup vs baseline: 1.5306x; 1.5306x over previous
//
#include <hip/hip_runtime.h>
#include <hip/hip_bf16.h>

// ShuffleNet fused block-MLP, MI355X (gfx950).  R14: NO LDS, NO BARRIERS.
// R13 ablation: all variants (no-gelu / no-GEMM2 / no-GEMM1) == 48us -> the
// stage+barrier+low-TLP skeleton was the cost, not any work inside it.
// Fix: x B-fragment transpose done IN REGISTERS via ds_bpermute (pure lane
// permutation), so the fused kernel is k2-shaped: short independent waves,
// contiguous loads, occupancy limited only by VGPR.
//   thread s loads x[rt*16 + (s>>2)][n*64 + ks*32 + (s&3)*8 .. +8) (32B, coalesced)
//   packs to 4x bf16-pair ints; dest lane l pulls word j from s=(l&15)*4+(l>>4)
//   -> exactly the B-frag element order of the proven R11 kernel.
// Math (pi-permuted w2 pack, register-local shuffle, epilogue) = R11, passed.

typedef __attribute__((ext_vector_type(8))) short  short8;   // 8 bf16 = 4 VGPR
typedef __attribute__((ext_vector_type(4))) short  short4v;
typedef __attribute__((ext_vector_type(4))) float  floatx4;

__device__ __forceinline__ short f2bf(float f) {
  union { __hip_bfloat16 h; short s; } u;
  u.h = __float2bfloat16(f);
  return u.s;
}
__device__ __forceinline__ float bf2f(short s) {
  union { float f; unsigned u; } uu;
  uu.u = ((unsigned)(unsigned short)s) << 16;
  return uu.f;
}
__device__ __forceinline__ int pk16(float a, float b) {
  return (int)(unsigned short)f2bf(a) | ((int)(unsigned short)f2bf(b) << 16);
}

// gelu(v) ~= v * sigmoid(1.5957691*(v + 0.044715 v^3)), exp2-folded (abs<5e-4)
__device__ __forceinline__ float gelu_f(float v) {
  float m = v * v;
  float c = fmaf(-0.1029375f, m, -2.3020807f);
  float z = v * c;
  float e = __builtin_amdgcn_exp2f(z);
  return v * __builtin_amdgcn_rcpf(1.0f + e);
}

// ---- pack kernel: w1 frags | w2 frags (pi-permuted) | b1 frags (bf16) ----
__global__ void pack_k(const float* __restrict__ w1, const float* __restrict__ w2,
                       const float* __restrict__ b1, short* __restrict__ w1p,
                       short* __restrict__ w2p, short* __restrict__ b1p) {
  const int t = blockIdx.x * blockDim.x + threadIdx.x;  // 160*512 = 81920
  const int lane = t & 63;
  const int lhi = lane >> 4;
  if (t < 32768) {  // w1 frag (n,np,ks): lane l elem e = w1[n][np*16+(l&15)][ks*32+lhi*8+e]
    const int ks = (t >> 6) & 1, np = (t >> 7) & 15, n = (t >> 11) & 15;
    const float* src = w1 + ((size_t)(n * 256 + np * 16 + (lane & 15)) * 64 + ks * 32 + lhi * 8);
    short8 f;
#pragma unroll
    for (int e = 0; e < 8; ++e) f[e] = f2bf(src[e]);
    *(short8*)(w1p + (size_t)t * 8) = f;
  } else if (t < 65536) {  // w2 frag (np,s,ot), pi-permuted k
    const int t2 = t - 32768;
    const int ot = (t2 >> 6) & 3, s = (t2 >> 8) & 7, np = (t2 >> 11) & 15;
    const int op = ot * 16 + (lane & 15);
    short8 f;
#pragma unroll
    for (int e = 0; e < 8; ++e) {
      // physical k = s*32 + lhi*8 + e ; chunk index Kc = pi(k):
      const int Kc = 32 * s + 16 * ((e >> 2) & 1) + 4 * lhi + (e & 3);
      const int n = Kc >> 4, ohi = Kc & 15;
      f[e] = f2bf(w2[(size_t)(np * 64 + op) * 256 + ohi * 16 + n]);
    }
    *(short8*)(w2p + (size_t)t2 * 8) = f;
  } else {  // b1 frag (n,np): lane l reg r = bf16(b1[(np*16+lhi*4+r)*16+n])
    const int t3 = t - 65536;  // 16384
    const int np = (t3 >> 6) & 15, n = (t3 >> 10) & 15;
    short4v b;
#pragma unroll
    for (int r = 0; r < 4; ++r) b[r] = f2bf(b1[(np * 16 + lhi * 4 + r) * 16 + n]);
    *(short4v*)(b1p + (size_t)((n * 16 + np) * 64 + lane) * 4) = b;
  }
}

// ---- fused: 2048 WGs x 256 thr; WG = (rt = b&511, npq = b>>9); NO LDS ----
__global__ __launch_bounds__(256, 4) void fused_k(
    const float* __restrict__ x, const short* __restrict__ w1p,
    const short* __restrict__ w2p, const short* __restrict__ b1p,
    const float* __restrict__ b2, float* __restrict__ y) {
  const int tid = threadIdx.x;
  const int wv = tid >> 6, lane = tid & 63;
  const int l15 = lane & 15, lhi = lane >> 4;
  const int rt  = blockIdx.x & 511;            // x-sharing WGs 512 apart -> same XCD
  const int np  = (blockIdx.x >> 9) * 4 + wv;

  // x load geometry: this thread loads rows (lane>>2), col-octet (lane&3)
  const float* xbase = x + (size_t)(rt * 16 + (lane >> 2)) * 1024 + (lane & 3) * 8;
  // bpermute byte index: dest lane l pulls from source lane (l&15)*4 + (l>>4)
  const int pidx = (((l15 << 2) | lhi) << 2);

  floatx4 c0 = {0.f,0.f,0.f,0.f}, c1 = {0.f,0.f,0.f,0.f};
  floatx4 c2 = {0.f,0.f,0.f,0.f}, c3 = {0.f,0.f,0.f,0.f};

#pragma unroll
  for (int s = 0; s < 8; ++s) {
    union { int i[4]; short8 v; } af;

#pragma unroll
    for (int half = 0; half < 2; ++half) {
      const int n = 2 * s + half;
      // coalesced x loads (nt: keep L2 for weights; x re-reads hit L3)
      const float* p0 = xbase + n * 64;        // ks = 0
      const float* p1 = p0 + 32;               // ks = 1
      floatx4 q0 = __builtin_nontemporal_load((const floatx4*)p0);
      floatx4 q1 = __builtin_nontemporal_load((const floatx4*)(p0 + 4));
      floatx4 q2 = __builtin_nontemporal_load((const floatx4*)p1);
      floatx4 q3 = __builtin_nontemporal_load((const floatx4*)(p1 + 4));
      short8 wf0 = *(const short8*)(w1p + (size_t)(((n * 16 + np) * 2 + 0) * 64 + lane) * 8);
      short8 wf1 = *(const short8*)(w1p + (size_t)(((n * 16 + np) * 2 + 1) * 64 + lane) * 8);
      short4v bv = *(const short4v*)(b1p + (size_t)((n * 16 + np) * 64 + lane) * 4);

      // pack to bf16 pairs (source-lane order), then lane-permute to B-frag
      const int i00 = pk16(q0[0], q0[1]), i01 = pk16(q0[2], q0[3]);
      const int i02 = pk16(q1[0], q1[1]), i03 = pk16(q1[2], q1[3]);
      const int i10 = pk16(q2[0], q2[1]), i11 = pk16(q2[2], q2[3]);
      const int i12 = pk16(q3[0], q3[1]), i13 = pk16(q3[2], q3[3]);
      union { int i[4]; short8 v; } xf0, xf1;
      xf0.i[0] = __builtin_amdgcn_ds_bpermute(pidx, i00);
      xf0.i[1] = __builtin_amdgcn_ds_bpermute(pidx, i01);
      xf0.i[2] = __builtin_amdgcn_ds_bpermute(pidx, i02);
      xf0.i[3] = __builtin_amdgcn_ds_bpermute(pidx, i03);
      xf1.i[0] = __builtin_amdgcn_ds_bpermute(pidx, i10);
      xf1.i[1] = __builtin_amdgcn_ds_bpermute(pidx, i11);
      xf1.i[2] = __builtin_amdgcn_ds_bpermute(pidx, i12);
      xf1.i[3] = __builtin_amdgcn_ds_bpermute(pidx, i13);

      floatx4 acc = {0.f, 0.f, 0.f, 0.f};
      acc = __builtin_amdgcn_mfma_f32_16x16x32_bf16(wf0, xf0.v, acc, 0, 0, 0);
      acc = __builtin_amdgcn_mfma_f32_16x16x32_bf16(wf1, xf1.v, acc, 0, 0, 0);
      af.i[2 * half + 0] = pk16(gelu_f(acc[0] + bf2f(bv[0])), gelu_f(acc[1] + bf2f(bv[1])));
      af.i[2 * half + 1] = pk16(gelu_f(acc[2] + bf2f(bv[2])), gelu_f(acc[3] + bf2f(bv[3])));
    }

    // ---- GEMM2 slice s: A-frag is this lane's own registers ----
    const size_t wb = (size_t)((np * 8 + s) * 4) * 64 * 8;
    short8 bf0  = *(const short8*)(w2p + wb + (size_t)(0 * 64 + lane) * 8);
    short8 bf1  = *(const short8*)(w2p + wb + (size_t)(1 * 64 + lane) * 8);
    short8 bf2v = *(const short8*)(w2p + wb + (size_t)(2 * 64 + lane) * 8);
    short8 bf3  = *(const short8*)(w2p + wb + (size_t)(3 * 64 + lane) * 8);
    c0 = __builtin_amdgcn_mfma_f32_16x16x32_bf16(af.v, bf0,  c0, 0, 0, 0);
    c1 = __builtin_amdgcn_mfma_f32_16x16x32_bf16(af.v, bf1,  c1, 0, 0, 0);
    c2 = __builtin_amdgcn_mfma_f32_16x16x32_bf16(af.v, bf2v, c2, 0, 0, 0);
    c3 = __builtin_amdgcn_mfma_f32_16x16x32_bf16(af.v, bf3,  c3, 0, 0, 0);
  }

  // ---- y store: col = np*64 + ot*16 + l15, rows rt*16 + lhi*4 + r ----
  floatx4 cc[4] = {c0, c1, c2, c3};
#pragma unroll
  for (int ot = 0; ot < 4; ++ot) {
    const int col = np * 64 + ot * 16 + l15;
    const float bb = b2[col];
    float* py = y + (size_t)(rt * 16 + lhi * 4) * 1024 + col;
#pragma unroll
    for (int r = 0; r < 4; ++r)
      py[(size_t)r * 1024] = cc[ot][r] + bb;
  }
}

extern "C" void kernel_launch(void* const* d_in, const int* in_sizes, int n_in,
                              void* d_out, int out_size, void* d_ws, size_t ws_size,
                              hipStream_t stream) {
  const float* x  = (const float*)d_in[0];
  const float* w1 = (const float*)d_in[1];
  const float* b1 = (const float*)d_in[2];
  const float* w2 = (const float*)d_in[3];
  const float* b2 = (const float*)d_in[4];
  float* y = (float*)d_out;

  short* w1p = (short*)d_ws;               // 512 KB
  short* w2p = w1p + 16 * 256 * 64;        // 512 KB
  short* b1p = w2p + 16 * 256 * 64;        // 128 KB

  pack_k<<<160, 512, 0, stream>>>(w1, w2, b1, w1p, w2p, b1p);
  fused_k<<<2048, 256, 0, stream>>>(x, w1p, w2p, b1p, b2, y);
}

// Round 15
// 57.215 us; speedup vs baseline: 3.0444x; 1.9890x over previous
//
#include <hip/hip_runtime.h>
#include <hip/hip_bf16.h>

// ShuffleNet fused block-MLP, MI355X (gfx950).  R15: x pre-transposed to
// MFMA fragment order by a streaming kernel; main kernel is a k2 clone:
// NO LDS, NO barriers, NO f32 loads, NO cvt on the load path — only
// independent contiguous bf16 frag loads. (R13-V3 48us vs R4-k2 11.5us
// isolated the stage+barrier prologue as the 4x binder; this removes it.)
// x:(8192,1024) f32; w1:(16,256,64); b1:(4096); w2:(16,64,256); b2:(1024); y f32.
//   h[b,n,o] = sum_i x[b,n*64+i]*w1[n,o,i];  shuffled j = o*16+n
//   g = gelu(h+b1);  y[b,np*64+o'] = sum_K g[b,np*256+K]*w2'[np,o',K] + b2
// Register-local shuffle via pi-permuted w2 pack (R11, passed):
//   pi(k) = 32*(k>>5) + 16*((k>>2)&1) + 4*((k>>3)&3) + (k&3); GEMM2 A-frag of
//   slice s = this lane's own packed GEMM1 outputs for n=2s,2s+1.
// xT frag (rt,n,ks): lane l elem e = bf16(x[rt*16+(l&15)][n*64+ks*32+(l>>4)*8+e])
//   stored at xT[((rt*16+n)*2+ks)*512 + l*8 + e]  (1KB/wave contiguous).

typedef __attribute__((ext_vector_type(8))) short  short8;   // 8 bf16 = 4 VGPR
typedef __attribute__((ext_vector_type(4))) short  short4v;
typedef __attribute__((ext_vector_type(4))) float  floatx4;

__device__ __forceinline__ short f2bf(float f) {
  union { __hip_bfloat16 h; short s; } u;
  u.h = __float2bfloat16(f);
  return u.s;
}
__device__ __forceinline__ float bf2f(short s) {
  union { float f; unsigned u; } uu;
  uu.u = ((unsigned)(unsigned short)s) << 16;
  return uu.f;
}
__device__ __forceinline__ int pk16(float a, float b) {
  return (int)(unsigned short)f2bf(a) | ((int)(unsigned short)f2bf(b) << 16);
}

// gelu(v) ~= v * sigmoid(1.5957691*(v + 0.044715 v^3)), exp2-folded (abs<5e-4)
__device__ __forceinline__ float gelu_f(float v) {
  float m = v * v;
  float c = fmaf(-0.1029375f, m, -2.3020807f);
  float z = v * c;
  float e = __builtin_amdgcn_exp2f(z);
  return v * __builtin_amdgcn_rcpf(1.0f + e);
}

// ---- pack kernel: w1 frags | w2 frags (pi-permuted) | b1 frags (bf16) ----
__global__ void pack_k(const float* __restrict__ w1, const float* __restrict__ w2,
                       const float* __restrict__ b1, short* __restrict__ w1p,
                       short* __restrict__ w2p, short* __restrict__ b1p) {
  const int t = blockIdx.x * blockDim.x + threadIdx.x;  // 160*512 = 81920
  const int lane = t & 63;
  const int lhi = lane >> 4;
  if (t < 32768) {  // w1 frag (n,np,ks): lane l elem e = w1[n][np*16+(l&15)][ks*32+lhi*8+e]
    const int ks = (t >> 6) & 1, np = (t >> 7) & 15, n = (t >> 11) & 15;
    const float* src = w1 + ((size_t)(n * 256 + np * 16 + (lane & 15)) * 64 + ks * 32 + lhi * 8);
    short8 f;
#pragma unroll
    for (int e = 0; e < 8; ++e) f[e] = f2bf(src[e]);
    *(short8*)(w1p + (size_t)t * 8) = f;
  } else if (t < 65536) {  // w2 frag (np,s,ot), pi-permuted k
    const int t2 = t - 32768;
    const int ot = (t2 >> 6) & 3, s = (t2 >> 8) & 7, np = (t2 >> 11) & 15;
    const int op = ot * 16 + (lane & 15);
    short8 f;
#pragma unroll
    for (int e = 0; e < 8; ++e) {
      const int Kc = 32 * s + 16 * ((e >> 2) & 1) + 4 * lhi + (e & 3);
      const int n = Kc >> 4, ohi = Kc & 15;
      f[e] = f2bf(w2[(size_t)(np * 64 + op) * 256 + ohi * 16 + n]);
    }
    *(short8*)(w2p + (size_t)t2 * 8) = f;
  } else {  // b1 frag (n,np): lane l reg r = bf16(b1[(np*16+lhi*4+r)*16+n])
    const int t3 = t - 65536;  // 16384
    const int np = (t3 >> 6) & 15, n = (t3 >> 10) & 15;
    short4v b;
#pragma unroll
    for (int r = 0; r < 4; ++r) b[r] = f2bf(b1[(np * 16 + lhi * 4 + r) * 16 + n]);
    *(short4v*)(b1p + (size_t)((n * 16 + np) * 64 + lane) * 4) = b;
  }
}

// ---- pack_x: x (f32, row-major) -> xT (bf16, B-frag order). Streaming. ----
// 2048 WGs x 256 thr; wave = (rt = b>>2, n = (b&3)*4 + wv).
// Lane gather is line-exact across the wave; x is read exactly once (NT).
__global__ __launch_bounds__(256, 4) void pack_x(
    const float* __restrict__ x, short* __restrict__ xT) {
  const int tid = threadIdx.x;
  const int wv = tid >> 6, lane = tid & 63;
  const int l15 = lane & 15, lhi = lane >> 4;
  const int rt = blockIdx.x >> 2;
  const int n  = (blockIdx.x & 3) * 4 + wv;

  const float* px = x + (size_t)(rt * 16 + l15) * 1024 + n * 64 + lhi * 8;
#pragma unroll
  for (int ks = 0; ks < 2; ++ks) {
    floatx4 a = __builtin_nontemporal_load((const floatx4*)(px + ks * 32));
    floatx4 b = __builtin_nontemporal_load((const floatx4*)(px + ks * 32 + 4));
    short8 f;
#pragma unroll
    for (int e = 0; e < 4; ++e) { f[e] = f2bf(a[e]); f[e + 4] = f2bf(b[e]); }
    *(short8*)(xT + ((size_t)(rt * 16 + n) * 2 + ks) * 512 + lane * 8) = f;
  }
}

// ---- fused: 2048 WGs x 256 thr; WG = (rt = b&511, npq = b>>9); k2-shaped ----
__global__ __launch_bounds__(256, 4) void fused_k(
    const short* __restrict__ xT, const short* __restrict__ w1p,
    const short* __restrict__ w2p, const short* __restrict__ b1p,
    const float* __restrict__ b2, float* __restrict__ y) {
  const int tid = threadIdx.x;
  const int wv = tid >> 6, lane = tid & 63;
  const int l15 = lane & 15, lhi = lane >> 4;
  const int rt  = blockIdx.x & 511;            // x-sharing WGs 512 apart -> same XCD
  const int np  = (blockIdx.x >> 9) * 4 + wv;

  floatx4 c0 = {0.f,0.f,0.f,0.f}, c1 = {0.f,0.f,0.f,0.f};
  floatx4 c2 = {0.f,0.f,0.f,0.f}, c3 = {0.f,0.f,0.f,0.f};

#pragma unroll
  for (int s = 0; s < 8; ++s) {
    union { int i[4]; short8 v; } af;

#pragma unroll
    for (int half = 0; half < 2; ++half) {
      const int n = 2 * s + half;
      // all loads contiguous bf16 frags, mutually independent
      short8 xf0 = *(const short8*)(xT + ((size_t)(rt * 16 + n) * 2 + 0) * 512 + lane * 8);
      short8 xf1 = *(const short8*)(xT + ((size_t)(rt * 16 + n) * 2 + 1) * 512 + lane * 8);
      short8 wf0 = *(const short8*)(w1p + (size_t)(((n * 16 + np) * 2 + 0) * 64 + lane) * 8);
      short8 wf1 = *(const short8*)(w1p + (size_t)(((n * 16 + np) * 2 + 1) * 64 + lane) * 8);
      short4v bv = *(const short4v*)(b1p + (size_t)((n * 16 + np) * 64 + lane) * 4);
      floatx4 acc = {0.f, 0.f, 0.f, 0.f};
      acc = __builtin_amdgcn_mfma_f32_16x16x32_bf16(wf0, xf0, acc, 0, 0, 0);
      acc = __builtin_amdgcn_mfma_f32_16x16x32_bf16(wf1, xf1, acc, 0, 0, 0);
      af.i[2 * half + 0] = pk16(gelu_f(acc[0] + bf2f(bv[0])), gelu_f(acc[1] + bf2f(bv[1])));
      af.i[2 * half + 1] = pk16(gelu_f(acc[2] + bf2f(bv[2])), gelu_f(acc[3] + bf2f(bv[3])));
    }

    // GEMM2 slice s: A-frag is this lane's own registers (pi-fold)
    const size_t wb = (size_t)((np * 8 + s) * 4) * 64 * 8;
    short8 bf0  = *(const short8*)(w2p + wb + (size_t)(0 * 64 + lane) * 8);
    short8 bf1  = *(const short8*)(w2p + wb + (size_t)(1 * 64 + lane) * 8);
    short8 bf2v = *(const short8*)(w2p + wb + (size_t)(2 * 64 + lane) * 8);
    short8 bf3  = *(const short8*)(w2p + wb + (size_t)(3 * 64 + lane) * 8);
    c0 = __builtin_amdgcn_mfma_f32_16x16x32_bf16(af.v, bf0,  c0, 0, 0, 0);
    c1 = __builtin_amdgcn_mfma_f32_16x16x32_bf16(af.v, bf1,  c1, 0, 0, 0);
    c2 = __builtin_amdgcn_mfma_f32_16x16x32_bf16(af.v, bf2v, c2, 0, 0, 0);
    c3 = __builtin_amdgcn_mfma_f32_16x16x32_bf16(af.v, bf3,  c3, 0, 0, 0);
  }

  // y store (NT; never re-read): col = np*64+ot*16+l15, rows rt*16+lhi*4+r
  floatx4 cc[4] = {c0, c1, c2, c3};
#pragma unroll
  for (int ot = 0; ot < 4; ++ot) {
    const int col = np * 64 + ot * 16 + l15;
    const float bb = b2[col];
    float* py = y + (size_t)(rt * 16 + lhi * 4) * 1024 + col;
#pragma unroll
    for (int r = 0; r < 4; ++r)
      __builtin_nontemporal_store(cc[ot][r] + bb, py + (size_t)r * 1024);
  }
}

extern "C" void kernel_launch(void* const* d_in, const int* in_sizes, int n_in,
                              void* d_out, int out_size, void* d_ws, size_t ws_size,
                              hipStream_t stream) {
  const float* x  = (const float*)d_in[0];
  const float* w1 = (const float*)d_in[1];
  const float* b1 = (const float*)d_in[2];
  const float* w2 = (const float*)d_in[3];
  const float* b2 = (const float*)d_in[4];
  float* y = (float*)d_out;

  short* w1p = (short*)d_ws;               // 512 KB
  short* w2p = w1p + 16 * 256 * 64;        // 512 KB
  short* b1p = w2p + 16 * 256 * 64;        // 128 KB
  short* xT  = b1p + 16 * 16 * 64 * 4;     // 16 MB (bf16 fragment-order x)

  pack_k<<<160, 512, 0, stream>>>(w1, w2, b1, w1p, w2p, b1p);
  pack_x<<<2048, 256, 0, stream>>>(x, xT);
  fused_k<<<2048, 256, 0, stream>>>(xT, w1p, w2p, b1p, b2, y);
}